// Round 1
// 561.619 us; speedup vs baseline: 1.1303x; 1.1303x over previous
//
#include <hip/hip_runtime.h>
#include <math.h>

#define B_ 16
#define N_ 16384
#define R_ 1024
#define D_ 320
#define BINS_ 32
#define H_ 512
#define EPS_ 1e-5f
#define AP 516   // padded LDS stride for A (2-way conflict max -> free)
#define EP 260   // padded LDS stride for E

// Fused prep: blocks 0-4 segment offsets (binary search on sorted seg_ids),
// block 5 BN->W2 fold, blocks 6-37 zero the pooled accumulator.
__global__ __launch_bounds__(256) void k_prep(const int* __restrict__ seg,
                      const float* __restrict__ gamma, const float* __restrict__ beta,
                      const float* __restrict__ mean, const float* __restrict__ var,
                      const float* __restrict__ W2, const float* __restrict__ b2,
                      int* __restrict__ off, float* __restrict__ W2f,
                      float* __restrict__ bias3, float* __restrict__ pooled){
  __shared__ float red[3 * 256];
  int blk = blockIdx.x, tid = threadIdx.x;
  if (blk < 5){
    int g = blk * 256 + tid;
    if (g <= R_){
      int lo = 0, hi = N_;
      while (lo < hi){ int mid = (lo + hi) >> 1; if (seg[mid] < g) lo = mid + 1; else hi = mid; }
      off[g] = lo;
    }
  } else if (blk == 5){
    float p0 = 0.f, p1 = 0.f, p2 = 0.f;
    for (int h = tid; h < H_; h += 256){
      float c = gamma[h] / sqrtf(var[h] + EPS_);
      float d = beta[h] - mean[h] * c;
      float w0 = W2[h * 3 + 0], w1 = W2[h * 3 + 1], w2 = W2[h * 3 + 2];
      W2f[h * 3 + 0] = c * w0; W2f[h * 3 + 1] = c * w1; W2f[h * 3 + 2] = c * w2;
      p0 += d * w0; p1 += d * w1; p2 += d * w2;
    }
    red[tid] = p0; red[256 + tid] = p1; red[512 + tid] = p2;
    __syncthreads();
    for (int s = 128; s > 0; s >>= 1){
      if (tid < s){
        red[tid] += red[tid + s];
        red[256 + tid] += red[256 + tid + s];
        red[512 + tid] += red[512 + tid + s];
      }
      __syncthreads();
    }
    if (tid < 3) bias3[tid] = b2[tid] + red[tid * 256];
  } else {
    float4 z = {0.f, 0.f, 0.f, 0.f};
    float4* p4 = (float4*)pooled;
    const int total4 = B_ * R_ * BINS_ / 4;           // 131072
    for (int i = (blk - 6) * 256 + tid; i < total4; i += 32 * 256) p4[i] = z;
  }
}

// One WAVE per (64-row chunk, batch b) — no __syncthreads anywhere.
// Vectorized row read: lane owns cols {4l..4l+3} (float4) + col {256+l} (dword):
// 2 VMEM ops / 1280 B row instead of 5 dwords — more bytes per vmcnt slot.
__global__ __launch_bounds__(256) void k_pool(const float* __restrict__ x,
                                              const int* __restrict__ seg,
                                              float* __restrict__ pooled){
  __shared__ __align__(16) float red[4 * 320];
  int tid = threadIdx.x;
  int wid = tid >> 6, lane = tid & 63;
  int c = blockIdx.x * 4 + wid;        // 64-row chunk index
  int b = blockIdx.y;
  int base = c * 64;
  int my_seg = seg[base + lane];
  int prev = __shfl_up(my_seg, 1);
  bool bnd = (lane == 0) || (my_seg != prev);
  unsigned long long mask = __ballot(bnd);
  const float* xp = x + ((size_t)b * N_ + base) * D_;
  float* wred = &red[wid * 320];
  while (mask){
    int i = __builtin_ctzll(mask);
    mask &= mask - 1;
    int e = mask ? __builtin_ctzll(mask) : 64;
    int sg = __shfl(my_seg, i);
    float4 a0 = {0.f, 0.f, 0.f, 0.f};
    float a4 = 0.f;
    const float* rp  = xp + (size_t)i * D_ + 4 * lane;
    const float* rp1 = xp + (size_t)i * D_ + 256 + lane;
    for (int r = i; r < e; r++, rp += D_, rp1 += D_){
      float4 v = *(const float4*)rp;
      a0.x += v.x; a0.y += v.y; a0.z += v.z; a0.w += v.w;
      a4 += *rp1;
    }
    *(float4*)&wred[4 * lane] = a0;
    wred[256 + lane] = a4;
    if (lane < 32){
      float s = 0.f;
      #pragma unroll
      for (int j = 0; j < 10; j++) s += wred[lane * 10 + j];
      atomicAdd(&pooled[((size_t)b * R_ + sg) * BINS_ + lane], s);
    }
  }
}

// Register-tiled GEMM: A[r*16+b][h] = (pooled[b][r][:]*sc[r]) @ W1[:32][h] + b1[h].
// M=16384 (m = r*16+b), Ncol=512, K=32. 64x64 tile, 256 thr, 4x4 register tile:
// per k-step 1 ds_read_b128 (W) + 4 ds_read_b32 (P) feed 16 FMA — vs the old
// in-k_main A-stage's 1 ds_read per FMA.
__global__ __launch_bounds__(256) void k_feat(const float* __restrict__ pooled,
                      const float* __restrict__ W1, const float* __restrict__ b1,
                      const int* __restrict__ off, float* __restrict__ Ag){
  __shared__ float Pt[64][33];                       // [row][k], +1 pad
  __shared__ __align__(16) float Wt[32][64];         // [k][col]
  int tid = threadIdx.x;
  int c0 = blockIdx.x * 64;                          // col block (8)
  int m0 = blockIdx.y * 64;                          // row block (256)
  for (int i = tid; i < 64 * 32; i += 256){          // stage P (scaled), coalesced
    int row = i >> 5, k = i & 31;
    int m = m0 + row;
    int r = m >> 4, b = m & 15;
    int cnt = off[r + 1] - off[r];
    float sc = 1.0f / (10.0f * (float)(cnt > 0 ? cnt : 1));
    Pt[row][k] = pooled[(size_t)(b * R_ + r) * BINS_ + k] * sc;
  }
  for (int i = tid; i < 32 * 64; i += 256){          // stage W1 tile, coalesced
    int k = i >> 6, cc = i & 63;
    Wt[k][cc] = W1[k * H_ + c0 + cc];
  }
  __syncthreads();
  int ty = tid >> 4, tx = tid & 15;
  float acc[4][4];
  #pragma unroll
  for (int i = 0; i < 4; i++)
    #pragma unroll
    for (int j = 0; j < 4; j++) acc[i][j] = 0.f;
  #pragma unroll
  for (int k = 0; k < 32; k++){
    float4 wv = *(const float4*)&Wt[k][tx * 4];
    float p0 = Pt[ty * 4 + 0][k];
    float p1 = Pt[ty * 4 + 1][k];
    float p2 = Pt[ty * 4 + 2][k];
    float p3 = Pt[ty * 4 + 3][k];
    acc[0][0] = fmaf(p0, wv.x, acc[0][0]); acc[0][1] = fmaf(p0, wv.y, acc[0][1]);
    acc[0][2] = fmaf(p0, wv.z, acc[0][2]); acc[0][3] = fmaf(p0, wv.w, acc[0][3]);
    acc[1][0] = fmaf(p1, wv.x, acc[1][0]); acc[1][1] = fmaf(p1, wv.y, acc[1][1]);
    acc[1][2] = fmaf(p1, wv.z, acc[1][2]); acc[1][3] = fmaf(p1, wv.w, acc[1][3]);
    acc[2][0] = fmaf(p2, wv.x, acc[2][0]); acc[2][1] = fmaf(p2, wv.y, acc[2][1]);
    acc[2][2] = fmaf(p2, wv.z, acc[2][2]); acc[2][3] = fmaf(p2, wv.w, acc[2][3]);
    acc[3][0] = fmaf(p3, wv.x, acc[3][0]); acc[3][1] = fmaf(p3, wv.y, acc[3][1]);
    acc[3][2] = fmaf(p3, wv.z, acc[3][2]); acc[3][3] = fmaf(p3, wv.w, acc[3][3]);
  }
  float4 bv = *(const float4*)&b1[c0 + tx * 4];
  #pragma unroll
  for (int i = 0; i < 4; i++){
    float4 o = {acc[i][0] + bv.x, acc[i][1] + bv.y, acc[i][2] + bv.z, acc[i][3] + bv.w};
    *(float4*)&Ag[(size_t)(m0 + ty * 4 + i) * H_ + c0 + tx * 4] = o;
  }
}

// One block per segment. A-panel (16 b x 512 h) restaged from precomputed Ag
// with 8 coalesced float4 loads/thread (A-stage GEMM moved to k_feat).
// Per 16-atom tile: E[a][h] = cond[n]@W1[32:35,h] staged per 256-h chunk; each
// thread owns one (atom, b) pair and accumulates the 3-wide folded-W2 dot over h.
__global__ __launch_bounds__(256) void k_main(const float* __restrict__ Ag, const float* __restrict__ cond,
                      const float* __restrict__ W1,
                      const int* __restrict__ off, const float* __restrict__ W2f,
                      const float* __restrict__ bias3, float* __restrict__ out){
  __shared__ __align__(16) float A[B_ * AP];
  __shared__ __align__(16) float E[16 * EP];
  __shared__ float condT[16 * 3];
  int tid = threadIdx.x;
  int r = blockIdx.x;
  int s = off[r];
  int cnt = off[r + 1] - s;
  if (cnt == 0) return;   // uniform exit, before any sync

  const float4* Ag4 = (const float4*)(Ag + (size_t)r * (B_ * H_));
  for (int i = tid; i < B_ * H_ / 4; i += 256){       // 8 iters: 32 KB panel
    int b = i >> 7, h4 = i & 127;
    *(float4*)&A[b * AP + h4 * 4] = Ag4[i];
  }
  // A write->read ordered by the tile loop's syncs below.

  int a = tid >> 4, b = tid & 15;
  for (int t0 = 0; t0 < cnt; t0 += 16){
    int na = min(16, cnt - t0);
    __syncthreads();                        // prior E readers of condT done; orders A writes
    if (tid < 48){
      int aa = tid / 3, cc = tid % 3;
      condT[tid] = (aa < na) ? cond[(size_t)(s + t0 + aa) * 3 + cc] : 0.f;
    }
    __syncthreads();
    float o0 = 0.f, o1 = 0.f, o2 = 0.f;
    int ae = a < na ? a : 0;                // clamp: keep main loop non-divergent
    for (int hc = 0; hc < 2; hc++){
      int h = (hc << 8) + tid;
      float w0 = W1[32 * H_ + h], w1 = W1[33 * H_ + h], w2 = W1[34 * H_ + h];
      for (int aa = 0; aa < na; aa++)
        E[aa * EP + tid] = condT[aa * 3] * w0 + condT[aa * 3 + 1] * w1 + condT[aa * 3 + 2] * w2;
      __syncthreads();                      // also covers A write->read on first pass
      const float* Ap = &A[b * AP + (hc << 8)];
      const float* Ep = &E[ae * EP];
      const float* Wp = &W2f[(hc << 8) * 3];
      #pragma unroll 4
      for (int hp = 0; hp < 256; hp += 4){
        float4 av = *(const float4*)(Ap + hp);
        float4 ev = *(const float4*)(Ep + hp);
        const float* w = Wp + hp * 3;       // wave-uniform -> scalar loads
        float z;
        z = av.x + ev.x; z = fmaxf(z, 0.f); o0 = fmaf(z, w[0], o0); o1 = fmaf(z, w[1], o1); o2 = fmaf(z, w[2], o2);
        z = av.y + ev.y; z = fmaxf(z, 0.f); o0 = fmaf(z, w[3], o0); o1 = fmaf(z, w[4], o1); o2 = fmaf(z, w[5], o2);
        z = av.z + ev.z; z = fmaxf(z, 0.f); o0 = fmaf(z, w[6], o0); o1 = fmaf(z, w[7], o1); o2 = fmaf(z, w[8], o2);
        z = av.w + ev.w; z = fmaxf(z, 0.f); o0 = fmaf(z, w[9], o0); o1 = fmaf(z, w[10], o1); o2 = fmaf(z, w[11], o2);
      }
      __syncthreads();                      // protect E before next chunk/tile restage
    }
    if (a < na){
      size_t oi = ((size_t)b * N_ + (size_t)(s + t0 + a)) * 3;
      out[oi + 0] = o0 + bias3[0];
      out[oi + 1] = o1 + bias3[1];
      out[oi + 2] = o2 + bias3[2];
    }
  }
}

extern "C" void kernel_launch(void* const* d_in, const int* in_sizes, int n_in,
                              void* d_out, int out_size, void* d_ws, size_t ws_size,
                              hipStream_t stream) {
  const float* x      = (const float*)d_in[0];
  const float* cond   = (const float*)d_in[1];
  const int*   seg    = (const int*)  d_in[2];
  const float* W1     = (const float*)d_in[3];
  const float* b1     = (const float*)d_in[4];
  const float* gamma  = (const float*)d_in[5];
  const float* beta   = (const float*)d_in[6];
  const float* bnmean = (const float*)d_in[7];
  const float* bnvar  = (const float*)d_in[8];
  const float* W2     = (const float*)d_in[9];
  const float* b2     = (const float*)d_in[10];
  float* out = (float*)d_out;

  char* ws = (char*)d_ws;
  int*   seg_off = (int*)ws;                    // 1025 ints
  float* W2f     = (float*)(ws + 8192);         // 1536 floats
  float* bias3   = (float*)(ws + 14592);        // 3 floats
  float* pooled  = (float*)(ws + 16384);        // B*R*32 floats = 2 MB (raw sums)
  float* Ag      = (float*)(ws + (4u << 20));   // 16384 x 512 floats = 33.5 MB

  k_prep<<<dim3(38), dim3(256), 0, stream>>>(seg, gamma, beta, bnmean, bnvar, W2, b2,
                                             seg_off, W2f, bias3, pooled);
  k_pool<<<dim3(N_ / 64 / 4, B_), dim3(256), 0, stream>>>(x, seg, pooled);
  k_feat<<<dim3(8, 256), dim3(256), 0, stream>>>(pooled, W1, b1, seg_off, Ag);
  k_main<<<dim3(R_), dim3(256), 0, stream>>>(Ag, cond, W1, seg_off, W2f, bias3, out);
}

// Round 2
// 560.204 us; speedup vs baseline: 1.1331x; 1.0025x over previous
//
#include <hip/hip_runtime.h>
#include <math.h>

#define B_ 16
#define N_ 16384
#define R_ 1024
#define D_ 320
#define BINS_ 32
#define H_ 512
#define EPS_ 1e-5f
#define AP 516   // padded LDS stride for A (2-way conflict max -> free)
#define EP 260   // padded LDS stride for E

// Fused prep: blocks 0-4 segment offsets (binary search on sorted seg_ids),
// block 5 BN->W2 fold, blocks 6-37 zero the pooled accumulator.
__global__ __launch_bounds__(256) void k_prep(const int* __restrict__ seg,
                      const float* __restrict__ gamma, const float* __restrict__ beta,
                      const float* __restrict__ mean, const float* __restrict__ var,
                      const float* __restrict__ W2, const float* __restrict__ b2,
                      int* __restrict__ off, float* __restrict__ W2f,
                      float* __restrict__ bias3, float* __restrict__ pooled){
  __shared__ float red[3 * 256];
  int blk = blockIdx.x, tid = threadIdx.x;
  if (blk < 5){
    int g = blk * 256 + tid;
    if (g <= R_){
      int lo = 0, hi = N_;
      while (lo < hi){ int mid = (lo + hi) >> 1; if (seg[mid] < g) lo = mid + 1; else hi = mid; }
      off[g] = lo;
    }
  } else if (blk == 5){
    float p0 = 0.f, p1 = 0.f, p2 = 0.f;
    for (int h = tid; h < H_; h += 256){
      float c = gamma[h] / sqrtf(var[h] + EPS_);
      float d = beta[h] - mean[h] * c;
      float w0 = W2[h * 3 + 0], w1 = W2[h * 3 + 1], w2 = W2[h * 3 + 2];
      W2f[h * 3 + 0] = c * w0; W2f[h * 3 + 1] = c * w1; W2f[h * 3 + 2] = c * w2;
      p0 += d * w0; p1 += d * w1; p2 += d * w2;
    }
    red[tid] = p0; red[256 + tid] = p1; red[512 + tid] = p2;
    __syncthreads();
    for (int s = 128; s > 0; s >>= 1){
      if (tid < s){
        red[tid] += red[tid + s];
        red[256 + tid] += red[256 + tid + s];
        red[512 + tid] += red[512 + tid + s];
      }
      __syncthreads();
    }
    if (tid < 3) bias3[tid] = b2[tid] + red[tid * 256];
  } else {
    float4 z = {0.f, 0.f, 0.f, 0.f};
    float4* p4 = (float4*)pooled;
    const int total4 = B_ * R_ * BINS_ / 4;           // 131072
    for (int i = (blk - 6) * 256 + tid; i < total4; i += 32 * 256) p4[i] = z;
  }
}

// One WAVE per (64-row chunk, batch b) — no __syncthreads anywhere.
// Vectorized row read: lane owns cols {4l..4l+3} (float4) + col {256+l} (dword).
// Manual 2-row unroll: 4 VMEM ops in flight per step (vs 2), pairwise adds
// shorten the dependent accumulate chain.
__global__ __launch_bounds__(256) void k_pool(const float* __restrict__ x,
                                              const int* __restrict__ seg,
                                              float* __restrict__ pooled){
  __shared__ __align__(16) float red[4 * 320];
  int tid = threadIdx.x;
  int wid = tid >> 6, lane = tid & 63;
  int c = blockIdx.x * 4 + wid;        // 64-row chunk index
  int b = blockIdx.y;
  int base = c * 64;
  int my_seg = seg[base + lane];
  int prev = __shfl_up(my_seg, 1);
  bool bnd = (lane == 0) || (my_seg != prev);
  unsigned long long mask = __ballot(bnd);
  const float* xp = x + ((size_t)b * N_ + base) * D_;
  float* wred = &red[wid * 320];
  while (mask){
    int i = __builtin_ctzll(mask);
    mask &= mask - 1;
    int e = mask ? __builtin_ctzll(mask) : 64;
    int sg = __shfl(my_seg, i);
    float4 a0 = {0.f, 0.f, 0.f, 0.f};
    float a4 = 0.f;
    const float* rp  = xp + (size_t)i * D_ + 4 * lane;
    const float* rp1 = xp + (size_t)i * D_ + 256 + lane;
    int r = i;
    for (; r + 2 <= e; r += 2, rp += 2 * D_, rp1 += 2 * D_){
      float4 v0 = *(const float4*)rp;
      float4 v1 = *(const float4*)(rp + D_);
      float  s0 = rp1[0];
      float  s1 = rp1[D_];
      a0.x += v0.x + v1.x; a0.y += v0.y + v1.y;
      a0.z += v0.z + v1.z; a0.w += v0.w + v1.w;
      a4 += s0 + s1;
    }
    if (r < e){
      float4 v0 = *(const float4*)rp;
      a0.x += v0.x; a0.y += v0.y; a0.z += v0.z; a0.w += v0.w;
      a4 += rp1[0];
    }
    *(float4*)&wred[4 * lane] = a0;
    wred[256 + lane] = a4;
    if (lane < 32){
      float s = 0.f;
      #pragma unroll
      for (int j = 0; j < 10; j++) s += wred[lane * 10 + j];
      atomicAdd(&pooled[((size_t)b * R_ + sg) * BINS_ + lane], s);
    }
  }
}

// One block per segment. Fused A-stage (former k_feat): P = scaled pooled row
// (16 b x 32 k) staged in 2 KB LDS; per thread h = {tid, tid+256}: 8 k-quads x
// {4 coalesced W1 loads + 16 ds_read_b128 broadcasts + 64 FMA} -> A in LDS.
// No Ag round-trip (saves 67 MB HBM + one launch).
// Per 16-atom tile: E[a][h] = cond[n]@W1[32:35,h] staged per 256-h chunk; each
// thread owns one (atom, b) pair and accumulates the 3-wide folded-W2 dot over h.
__global__ __launch_bounds__(256) void k_main(const float* __restrict__ pooled, const float* __restrict__ cond,
                      const float* __restrict__ W1, const float* __restrict__ b1,
                      const int* __restrict__ off, const float* __restrict__ W2f,
                      const float* __restrict__ bias3, float* __restrict__ out){
  __shared__ __align__(16) float P[B_ * BINS_];
  __shared__ __align__(16) float A[B_ * AP];
  __shared__ __align__(16) float E[16 * EP];
  __shared__ float condT[16 * 3];
  int tid = threadIdx.x;
  int r = blockIdx.x;
  int s = off[r];
  int cnt = off[r + 1] - s;
  if (cnt == 0) return;   // uniform exit, before any sync

  float sc = 1.0f / (float)(cnt * 10);
  for (int i = tid; i < B_ * BINS_; i += 256)
    P[i] = pooled[(size_t)((i >> 5) * R_ + r) * BINS_ + (i & 31)] * sc;
  __syncthreads();

  // A-stage: thread computes h = tid, tid+256 for all 16 b via b128 P-broadcasts
  #pragma unroll
  for (int hc = 0; hc < 2; hc++){
    int h = (hc << 8) + tid;
    float bb = b1[h];
    float acc[B_];
    #pragma unroll
    for (int b = 0; b < B_; b++) acc[b] = bb;
    #pragma unroll
    for (int k4 = 0; k4 < 8; k4++){
      float w0 = W1[(k4 * 4 + 0) * H_ + h];
      float w1 = W1[(k4 * 4 + 1) * H_ + h];
      float w2 = W1[(k4 * 4 + 2) * H_ + h];
      float w3 = W1[(k4 * 4 + 3) * H_ + h];
      #pragma unroll
      for (int b = 0; b < B_; b++){
        float4 p = *(const float4*)&P[b * BINS_ + k4 * 4];
        acc[b] = fmaf(p.x, w0, fmaf(p.y, w1, fmaf(p.z, w2, fmaf(p.w, w3, acc[b]))));
      }
    }
    #pragma unroll
    for (int b = 0; b < B_; b++) A[b * AP + h] = acc[b];
  }
  // A write->read ordered by the tile loop's syncs below.

  int a = tid >> 4, b = tid & 15;
  for (int t0 = 0; t0 < cnt; t0 += 16){
    int na = min(16, cnt - t0);
    __syncthreads();                        // prior E readers of condT done; orders A writes
    if (tid < 48){
      int aa = tid / 3, cc = tid % 3;
      condT[tid] = (aa < na) ? cond[(size_t)(s + t0 + aa) * 3 + cc] : 0.f;
    }
    __syncthreads();
    float o0 = 0.f, o1 = 0.f, o2 = 0.f;
    int ae = a < na ? a : 0;                // clamp: keep main loop non-divergent
    for (int hc = 0; hc < 2; hc++){
      int h = (hc << 8) + tid;
      float w0 = W1[32 * H_ + h], w1 = W1[33 * H_ + h], w2 = W1[34 * H_ + h];
      for (int aa = 0; aa < na; aa++)
        E[aa * EP + tid] = condT[aa * 3] * w0 + condT[aa * 3 + 1] * w1 + condT[aa * 3 + 2] * w2;
      __syncthreads();                      // also covers A write->read on first pass
      const float* Ap = &A[b * AP + (hc << 8)];
      const float* Ep = &E[ae * EP];
      const float* Wp = &W2f[(hc << 8) * 3];
      #pragma unroll 4
      for (int hp = 0; hp < 256; hp += 4){
        float4 av = *(const float4*)(Ap + hp);
        float4 ev = *(const float4*)(Ep + hp);
        const float* w = Wp + hp * 3;       // wave-uniform -> scalar loads
        float z;
        z = av.x + ev.x; z = fmaxf(z, 0.f); o0 = fmaf(z, w[0], o0); o1 = fmaf(z, w[1], o1); o2 = fmaf(z, w[2], o2);
        z = av.y + ev.y; z = fmaxf(z, 0.f); o0 = fmaf(z, w[3], o0); o1 = fmaf(z, w[4], o1); o2 = fmaf(z, w[5], o2);
        z = av.z + ev.z; z = fmaxf(z, 0.f); o0 = fmaf(z, w[6], o0); o1 = fmaf(z, w[7], o1); o2 = fmaf(z, w[8], o2);
        z = av.w + ev.w; z = fmaxf(z, 0.f); o0 = fmaf(z, w[9], o0); o1 = fmaf(z, w[10], o1); o2 = fmaf(z, w[11], o2);
      }
      __syncthreads();                      // protect E before next chunk/tile restage
    }
    if (a < na){
      size_t oi = ((size_t)b * N_ + (size_t)(s + t0 + a)) * 3;
      out[oi + 0] = o0 + bias3[0];
      out[oi + 1] = o1 + bias3[1];
      out[oi + 2] = o2 + bias3[2];
    }
  }
}

extern "C" void kernel_launch(void* const* d_in, const int* in_sizes, int n_in,
                              void* d_out, int out_size, void* d_ws, size_t ws_size,
                              hipStream_t stream) {
  const float* x      = (const float*)d_in[0];
  const float* cond   = (const float*)d_in[1];
  const int*   seg    = (const int*)  d_in[2];
  const float* W1     = (const float*)d_in[3];
  const float* b1     = (const float*)d_in[4];
  const float* gamma  = (const float*)d_in[5];
  const float* beta   = (const float*)d_in[6];
  const float* bnmean = (const float*)d_in[7];
  const float* bnvar  = (const float*)d_in[8];
  const float* W2     = (const float*)d_in[9];
  const float* b2     = (const float*)d_in[10];
  float* out = (float*)d_out;

  char* ws = (char*)d_ws;
  int*   seg_off = (int*)ws;                    // 1025 ints
  float* W2f     = (float*)(ws + 8192);         // 1536 floats
  float* bias3   = (float*)(ws + 14592);        // 3 floats
  float* pooled  = (float*)(ws + 16384);        // B*R*32 floats = 2 MB (raw sums)

  k_prep<<<dim3(38), dim3(256), 0, stream>>>(seg, gamma, beta, bnmean, bnvar, W2, b2,
                                             seg_off, W2f, bias3, pooled);
  k_pool<<<dim3(N_ / 64 / 4, B_), dim3(256), 0, stream>>>(x, seg, pooled);
  k_main<<<dim3(R_), dim3(256), 0, stream>>>(pooled, cond, W1, b1, seg_off, W2f, bias3, out);
}